// Round 5
// baseline (200.829 us; speedup 1.0000x reference)
//
#include <hip/hip_runtime.h>
#include <stdint.h>

typedef __attribute__((ext_vector_type(2))) float fx2;
typedef __attribute__((ext_vector_type(4))) float fx4;
typedef __attribute__((ext_vector_type(8))) short short8;

#define MFMA(a,b,c) __builtin_amdgcn_mfma_f32_16x16x32_bf16(a,b,c,0,0,0)

union Frag { uint32_t u[4]; short8 s; };

// round-nearest-even to bf16, kept as fp32 bit pattern (low 16 zero)
__device__ __forceinline__ uint32_t bf16rne(float x) {
    uint32_t u = __float_as_uint(x);
    return (u + 0x7FFFu + ((u >> 16) & 1u)) & 0xFFFF0000u;
}

// split fp32 into hi=bf16(RNE) + lo=bf16(RNE of exact residual); pack two
// values' halves into one dword (a -> low16, b -> high16).
__device__ __forceinline__ void packsplit(float a, float b, uint32_t& hi, uint32_t& lo) {
    uint32_t ha = bf16rne(a), hb = bf16rne(b);
    float ra = a - __uint_as_float(ha);   // exact (Sterbenz)
    float rb = b - __uint_as_float(hb);
    hi = (ha >> 16) | (hb & 0xFFFF0000u);
    lo = (bf16rne(ra) >> 16) | (bf16rne(rb) & 0xFFFF0000u);
}

// v_pk_fma_f32 with op_sel broadcast variants
__device__ __forceinline__ fx2 pkfma_bLO(fx2 a, fx2 b, fx2 c) {
    fx2 d; asm("v_pk_fma_f32 %0, %1, %2, %3 op_sel:[0,0,0] op_sel_hi:[1,0,1]"
               : "=v"(d) : "v"(a), "v"(b), "v"(c)); return d;
}
__device__ __forceinline__ fx2 pkfma_bHI(fx2 a, fx2 b, fx2 c) {
    fx2 d; asm("v_pk_fma_f32 %0, %1, %2, %3 op_sel:[0,1,0] op_sel_hi:[1,1,1]"
               : "=v"(d) : "v"(a), "v"(b), "v"(c)); return d;
}
__device__ __forceinline__ fx2 pkfma_bHI_cLO(fx2 a, fx2 b, fx2 c) {
    fx2 d; asm("v_pk_fma_f32 %0, %1, %2, %3 op_sel:[0,1,0] op_sel_hi:[1,1,0]"
               : "=v"(d) : "v"(a), "v"(b), "v"(c)); return d;
}

// LDS dwords: buf0 hi@0 lo@2304 | buf1 hi@4608 lo@6912 | weights @9216
// Buffers hold either a K chunk (64 m x 64 k) or a Vt chunk (64 d x 64 m),
// rows padded to 36 dw. Double-buffered within each phase.
__global__ __launch_bounds__(256, 2)
void msmha_v5(const float* __restrict__ qg, const float* __restrict__ kg,
              const float* __restrict__ vg, const float* __restrict__ Dg,
              const float* __restrict__ m1w, const float* __restrict__ m1b,
              const float* __restrict__ m2w, const float* __restrict__ m2b,
              float* __restrict__ outg) {
    __shared__ __align__(16) uint32_t sm[9284];
    float* smF = (float*)sm;

    const int tid  = threadIdx.x;
    const int w    = tid >> 6, lane = tid & 63;
    const int col  = lane & 15, Q = lane >> 4;

    const int bid  = blockIdx.x;
    const int tile = bid & 7, bh = bid >> 3;
    const int h    = bh & 15, b = bh >> 4;
    const int t0g  = tile * 64;

    const size_t base = (size_t)bh * 512 * 64;

    if (tid < 16) {
        smF[9216 + 4*tid + 0] = m1w[h*32 + tid];       // w1_dot
        smF[9216 + 4*tid + 1] = m1w[h*32 + 16 + tid];  // w1_dist
        smF[9216 + 4*tid + 2] = m1b[h*16 + tid];       // b1
        smF[9216 + 4*tid + 3] = m2w[h*16 + tid];       // w2
    }
    const float b2v = m2b[h];

    const int trow = t0g + w*16 + col;
    // Q fragments (B operand: n=col=t, k=Q*8+j), pre-scaled by 1/sqrt(64)
    Frag qh[2], ql[2];
    {
        const float* qr = qg + base + (size_t)trow * 64;
#pragma unroll
        for (int ks = 0; ks < 2; ++ks) {
            fx4 f0 = *(const fx4*)(qr + ks*32 + Q*8);
            fx4 f1 = *(const fx4*)(qr + ks*32 + Q*8 + 4);
            f0 *= 0.125f; f1 *= 0.125f;
            packsplit(f0.x, f0.y, qh[ks].u[0], ql[ks].u[0]);
            packsplit(f0.z, f0.w, qh[ks].u[1], ql[ks].u[1]);
            packsplit(f1.x, f1.y, qh[ks].u[2], ql[ks].u[2]);
            packsplit(f1.z, f1.w, qh[ks].u[3], ql[ks].u[3]);
        }
    }
    const float* Drow = Dg + ((size_t)b*512 + trow) * 512;

    fx4 accA[32];          // scores: t=col, m = c*64 + mt*16 + 4Q + r
    fx4 oacc[4] = {};      // O: t = 4Q+r, d = dt*16+col

    // staging coords
    const int k4 = tid & 15, mrow = tid >> 4;         // K: fixed k4, 4 rows
    const int vm2 = tid & 31, vd4 = tid >> 5;         // Vt: fixed m2, d4/d4+8

    // ===================== K phase (double-buffered) =====================
    {
        fx4 kreg[4];
#pragma unroll
        for (int it = 0; it < 4; ++it)
            kreg[it] = *(const fx4*)(kg + base + (size_t)(mrow + 16*it)*64 + 4*k4);
#pragma unroll
        for (int it = 0; it < 4; ++it) {
            uint32_t h0,l0,h1,l1;
            packsplit(kreg[it].x, kreg[it].y, h0, l0);
            packsplit(kreg[it].z, kreg[it].w, h1, l1);
            const int ro = (mrow + 16*it)*36 + 2*k4;
            *(uint2*)(sm + ro)        = make_uint2(h0,h1);
            *(uint2*)(sm + 2304 + ro) = make_uint2(l0,l1);
        }
    }
    __syncthreads();

#pragma unroll 1
    for (int c = 0; c < 8; ++c) {
        const int cur = (c & 1) * 4608;
        fx4 knext[4];
        if (c < 7) {
#pragma unroll
            for (int it = 0; it < 4; ++it)
                knext[it] = *(const fx4*)(kg + base + (size_t)((c+1)*64 + mrow + 16*it)*64 + 4*k4);
        }
        fx4 dv[4];
#pragma unroll
        for (int mt = 0; mt < 4; ++mt)
            dv[mt] = *(const fx4*)(Drow + c*64 + mt*16 + 4*Q);

        // S^T = K·Q^T, 4-term split
#pragma unroll
        for (int mt = 0; mt < 4; ++mt) {
            fx4 acc = {};
#pragma unroll
            for (int ks = 0; ks < 2; ++ks) {
                const int ro = cur + (mt*16 + col)*36 + ks*16 + 4*Q;
                Frag ah, al;
                ah.s = *(short8*)(sm + ro);
                al.s = *(short8*)(sm + 2304 + ro);
                acc = MFMA(ah.s, qh[ks].s, acc);
                acc = MFMA(ah.s, ql[ks].s, acc);
                acc = MFMA(al.s, qh[ks].s, acc);
                acc = MFMA(al.s, ql[ks].s, acc);
            }
            accA[c*4 + mt] = acc;
        }

        // fused MLP (packed fp32)
        fx2 S2[8], D2[8], mix[8];
#pragma unroll
        for (int mt = 0; mt < 4; ++mt) {
            S2[2*mt]   = fx2{accA[c*4+mt].x, accA[c*4+mt].y};
            S2[2*mt+1] = fx2{accA[c*4+mt].z, accA[c*4+mt].w};
            D2[2*mt]   = fx2{dv[mt].x, dv[mt].y};
            D2[2*mt+1] = fx2{dv[mt].z, dv[mt].w};
            mix[2*mt]  = fx2{b2v, b2v};
            mix[2*mt+1]= fx2{b2v, b2v};
        }
#pragma unroll 1
        for (int cc = 0; cc < 16; ++cc) {
            fx2 w01 = *(const fx2*)(smF + 9216 + 4*cc);      // {w1d, w1s}
            fx2 w23 = *(const fx2*)(smF + 9216 + 4*cc + 2);  // {b1, w2}
#pragma unroll
            for (int p = 0; p < 8; ++p) {
                fx2 dt_ = pkfma_bHI_cLO(D2[p], w01, w23);    // D*w1s + b1
                fx2 hh  = pkfma_bLO(S2[p], w01, dt_);        // + s*w1d
                fx2 rr  = { fmaxf(hh.x, 0.f), fmaxf(hh.y, 0.f) };
                mix[p]  = pkfma_bHI(rr, w23, mix[p]);        // += relu*w2
            }
        }
#pragma unroll
        for (int mt = 0; mt < 4; ++mt)
            accA[c*4+mt] = fx4{mix[2*mt].x, mix[2*mt].y, mix[2*mt+1].x, mix[2*mt+1].y};

        if (c < 7) {
            const int nxt = 4608 - cur;
#pragma unroll
            for (int it = 0; it < 4; ++it) {
                uint32_t h0,l0,h1,l1;
                packsplit(knext[it].x, knext[it].y, h0, l0);
                packsplit(knext[it].z, knext[it].w, h1, l1);
                const int ro = (mrow + 16*it)*36 + 2*k4;
                *(uint2*)(sm + nxt + ro)        = make_uint2(h0,h1);
                *(uint2*)(sm + nxt + 2304 + ro) = make_uint2(l0,l1);
            }
        }
        __syncthreads();
    }

    // ============ prefetch Vt chunk 0, softmax overlapping loads ============
    fx4 vreg[2][2];
#pragma unroll
    for (int it = 0; it < 2; ++it) {
        const float* vr = vg + base + (size_t)(2*vm2)*64 + 4*(vd4 + 8*it);
        vreg[it][0] = *(const fx4*)vr;
        vreg[it][1] = *(const fx4*)(vr + 64);
    }

    // full-row softmax in registers (rows t=col, lanes Q=0..3 hold m-quarters)
    {
        float mx = -3.0e38f;
#pragma unroll
        for (int i = 0; i < 32; ++i)
#pragma unroll
            for (int r = 0; r < 4; ++r) mx = fmaxf(mx, accA[i][r]);
        mx = fmaxf(mx, __shfl_xor(mx, 16, 64));
        mx = fmaxf(mx, __shfl_xor(mx, 32, 64));
        float sum = 0.f;
#pragma unroll
        for (int i = 0; i < 32; ++i)
#pragma unroll
            for (int r = 0; r < 4; ++r) {
                const float e = __expf(accA[i][r] - mx);
                accA[i][r] = e;
                sum += e;
            }
        sum += __shfl_xor(sum, 16, 64);
        sum += __shfl_xor(sum, 32, 64);
        const float rinv = 1.f / sum;
#pragma unroll
        for (int i = 0; i < 32; ++i)
#pragma unroll
            for (int r = 0; r < 4; ++r) accA[i][r] *= rinv;
    }

    // write Vt chunk 0 (bank-conflict-free: m2 varies across lanes)
#pragma unroll
    for (int it = 0; it < 2; ++it) {
        const int d4 = vd4 + 8*it;
#pragma unroll
        for (int i = 0; i < 4; ++i) {
            uint32_t hw, lw;
            packsplit(vreg[it][0][i], vreg[it][1][i], hw, lw);
            sm[(4*d4 + i)*36 + vm2]        = hw;
            sm[2304 + (4*d4 + i)*36 + vm2] = lw;
        }
    }
    __syncthreads();

    // ===================== PV phase (double-buffered) =====================
    const int sbase = col | ((lane & 16) << 1);   // col + 32*(Q&1)
#pragma unroll 1
    for (int c = 0; c < 8; ++c) {
        const int cur = (c & 1) * 4608;
        fx4 vnext[2][2];
        if (c < 7) {
#pragma unroll
            for (int it = 0; it < 2; ++it) {
                const float* vr = vg + base + (size_t)((c+1)*64 + 2*vm2)*64 + 4*(vd4 + 8*it);
                vnext[it][0] = *(const fx4*)vr;
                vnext[it][1] = *(const fx4*)(vr + 64);
            }
        }
#pragma unroll
        for (int s = 0; s < 2; ++s) {
            const fx4 e0 = accA[c*4 + 2*s], e1 = accA[c*4 + 2*s + 1];
            uint32_t ph[4], pl[4];
            packsplit(e0.x, e0.y, ph[0], pl[0]);
            packsplit(e0.z, e0.w, ph[1], pl[1]);
            packsplit(e1.x, e1.y, ph[2], pl[2]);
            packsplit(e1.z, e1.w, ph[3], pl[3]);
            Frag Ah, Al;
#pragma unroll
            for (int dd = 0; dd < 4; ++dd) {
                const int sl = sbase + ((dd >> 1) << 4);
                const int pi = dd & 1;
                uint32_t h0 = (uint32_t)__shfl((int)ph[pi],   sl, 64);
                uint32_t h1 = (uint32_t)__shfl((int)ph[2+pi], sl, 64);
                uint32_t l0 = (uint32_t)__shfl((int)pl[pi],   sl, 64);
                uint32_t l1 = (uint32_t)__shfl((int)pl[2+pi], sl, 64);
                Ah.u[dd] = (lane & 32) ? h1 : h0;
                Al.u[dd] = (lane & 32) ? l1 : l0;
            }
#pragma unroll
            for (int dt = 0; dt < 4; ++dt) {
                const int vo = cur + (dt*16 + col)*36 + s*16 + 4*Q;
                Frag bh_, bl_;
                bh_.s = *(short8*)(sm + vo);
                bl_.s = *(short8*)(sm + vo + 2304);
                oacc[dt] = MFMA(Ah.s, bh_.s, oacc[dt]);
                oacc[dt] = MFMA(Ah.s, bl_.s, oacc[dt]);
                oacc[dt] = MFMA(Al.s, bh_.s, oacc[dt]);
            }
        }
        if (c < 7) {
            const int nxt = 4608 - cur;
#pragma unroll
            for (int it = 0; it < 2; ++it) {
                const int d4 = vd4 + 8*it;
#pragma unroll
                for (int i = 0; i < 4; ++i) {
                    uint32_t hw, lw;
                    packsplit(vnext[it][0][i], vnext[it][1][i], hw, lw);
                    sm[nxt + (4*d4 + i)*36 + vm2]        = hw;
                    sm[nxt + 2304 + (4*d4 + i)*36 + vm2] = lw;
                }
            }
        }
        __syncthreads();
    }

    // epilogue: O rows t = w*16 + 4Q + r, cols d = dt*16 + col
    const size_t ob = ((size_t)b*512 + t0g + w*16 + 4*Q)*1024 + h*64 + col;
#pragma unroll
    for (int dt = 0; dt < 4; ++dt) {
        const fx4 o4 = oacc[dt];
#pragma unroll
        for (int r = 0; r < 4; ++r)
            outg[ob + (size_t)r*1024 + dt*16] = o4[r];
    }
}

extern "C" void kernel_launch(void* const* d_in, const int* in_sizes, int n_in,
                              void* d_out, int out_size, void* d_ws, size_t ws_size,
                              hipStream_t stream) {
    const float* q   = (const float*)d_in[0];
    const float* k   = (const float*)d_in[1];
    const float* v   = (const float*)d_in[2];
    const float* dtm = (const float*)d_in[3];
    const float* m1w = (const float*)d_in[4];
    const float* m1b = (const float*)d_in[5];
    const float* m2w = (const float*)d_in[6];
    const float* m2b = (const float*)d_in[7];
    float* out = (float*)d_out;

    dim3 grid(64 * 8);    // (b,h) x 8 T-tiles of 64 rows
    dim3 block(256);
    msmha_v5<<<grid, block, 0, stream>>>(q, k, v, dtm, m1w, m1b, m2w, m2b, out);
}

// Round 7
// 143.407 us; speedup vs baseline: 1.4004x; 1.4004x over previous
//
#include <hip/hip_runtime.h>
#include <stdint.h>

typedef __attribute__((ext_vector_type(4))) float fx4;
typedef __attribute__((ext_vector_type(8))) short short8;

#define MFMA(a,b,c) __builtin_amdgcn_mfma_f32_16x16x32_bf16(a,b,c,0,0,0)

union Frag { uint32_t u[4]; short8 s; };

// round-nearest-even to bf16, kept as fp32 bit pattern (low 16 zero)
__device__ __forceinline__ uint32_t bf16rne(float x) {
    uint32_t u = __float_as_uint(x);
    return (u + 0x7FFFu + ((u >> 16) & 1u)) & 0xFFFF0000u;
}

// split fp32 into hi=bf16(RNE) + lo=bf16(RNE of exact residual); pack two
// values' halves into one dword (a -> low16, b -> high16).
__device__ __forceinline__ void packsplit(float a, float b, uint32_t& hi, uint32_t& lo) {
    uint32_t ha = bf16rne(a), hb = bf16rne(b);
    float ra = a - __uint_as_float(ha);   // exact (Sterbenz)
    float rb = b - __uint_as_float(hb);
    hi = (ha >> 16) | (hb & 0xFFFF0000u);
    lo = (bf16rne(ra) >> 16) | (bf16rne(rb) & 0xFFFF0000u);
}

// LDS dwords: buf0 hi@0 lo@2304 | buf1 hi@4608 lo@6912 | weights @9216
// Buffers hold either a K chunk (64 m x 64 k) or a Vt chunk (64 d x 64 m),
// rows padded to 36 dw. Double-buffered within each phase.
__global__ __launch_bounds__(256, 2)
void msmha_v7(const float* __restrict__ qg, const float* __restrict__ kg,
              const float* __restrict__ vg, const float* __restrict__ Dg,
              const float* __restrict__ m1w, const float* __restrict__ m1b,
              const float* __restrict__ m2w, const float* __restrict__ m2b,
              float* __restrict__ outg) {
    __shared__ __align__(16) uint32_t sm[9284];
    float* smF = (float*)sm;

    const int tid  = threadIdx.x;
    const int w    = tid >> 6, lane = tid & 63;
    const int col  = lane & 15, Q = lane >> 4;

    const int bid  = blockIdx.x;
    const int tile = bid & 7, bh = bid >> 3;
    const int h    = bh & 15, b = bh >> 4;
    const int t0g  = tile * 64;

    const size_t base = (size_t)bh * 512 * 64;

    if (tid < 16) {
        smF[9216 + 4*tid + 0] = m1w[h*32 + tid];       // w1_dot
        smF[9216 + 4*tid + 1] = m1w[h*32 + 16 + tid];  // w1_dist
        smF[9216 + 4*tid + 2] = m1b[h*16 + tid];       // b1
        smF[9216 + 4*tid + 3] = m2w[h*16 + tid];       // w2
    }
    const float b2v = m2b[h];

    const int trow = t0g + w*16 + col;
    // Q fragments (B operand: n=col=t, k=Q*8+j), pre-scaled by 1/sqrt(64)
    Frag qh[2], ql[2];
    {
        const float* qr = qg + base + (size_t)trow * 64;
#pragma unroll
        for (int ks = 0; ks < 2; ++ks) {
            fx4 f0 = *(const fx4*)(qr + ks*32 + Q*8);
            fx4 f1 = *(const fx4*)(qr + ks*32 + Q*8 + 4);
            f0 *= 0.125f; f1 *= 0.125f;
            packsplit(f0.x, f0.y, qh[ks].u[0], ql[ks].u[0]);
            packsplit(f0.z, f0.w, qh[ks].u[1], ql[ks].u[1]);
            packsplit(f1.x, f1.y, qh[ks].u[2], ql[ks].u[2]);
            packsplit(f1.z, f1.w, qh[ks].u[3], ql[ks].u[3]);
        }
    }
    const float* Drow = Dg + ((size_t)b*512 + trow) * 512;

    fx4 accA[32];          // scores: t=col, m = c*64 + mt*16 + 4Q + r (static idx)
    fx4 oacc[4] = {};      // O: t = 4Q+r, d = dt*16+col

    // staging coords
    const int k4 = tid & 15, mrow = tid >> 4;         // K: fixed k4, 4 rows
    const int vm2 = tid & 31, vd4 = tid >> 5;         // Vt: fixed m2, d4/d4+8

    // ===================== K phase (double-buffered) =====================
    {
        fx4 kreg[4];
#pragma unroll
        for (int it = 0; it < 4; ++it)
            kreg[it] = *(const fx4*)(kg + base + (size_t)(mrow + 16*it)*64 + 4*k4);
#pragma unroll
        for (int it = 0; it < 4; ++it) {
            uint32_t h0,l0,h1,l1;
            packsplit(kreg[it].x, kreg[it].y, h0, l0);
            packsplit(kreg[it].z, kreg[it].w, h1, l1);
            const int ro = (mrow + 16*it)*36 + 2*k4;
            *(uint2*)(sm + ro)        = make_uint2(h0,h1);
            *(uint2*)(sm + 2304 + ro) = make_uint2(l0,l1);
        }
    }
    __syncthreads();

#pragma unroll
    for (int c = 0; c < 8; ++c) {
        const int cur = (c & 1) * 4608;
        fx4 knext[4];
        if (c < 7) {
#pragma unroll
            for (int it = 0; it < 4; ++it)
                knext[it] = *(const fx4*)(kg + base + (size_t)((c+1)*64 + mrow + 16*it)*64 + 4*k4);
        }
        fx4 dv[4];
#pragma unroll
        for (int mt = 0; mt < 4; ++mt)
            dv[mt] = *(const fx4*)(Drow + c*64 + mt*16 + 4*Q);

        // S^T = K·Q^T, 4-term split
#pragma unroll
        for (int mt = 0; mt < 4; ++mt) {
            fx4 acc = {};
#pragma unroll
            for (int ks = 0; ks < 2; ++ks) {
                const int ro = cur + (mt*16 + col)*36 + ks*16 + 4*Q;
                Frag ah, al;
                ah.s = *(short8*)(sm + ro);
                al.s = *(short8*)(sm + 2304 + ro);
                acc = MFMA(ah.s, qh[ks].s, acc);
                acc = MFMA(ah.s, ql[ks].s, acc);
                acc = MFMA(al.s, qh[ks].s, acc);
                acc = MFMA(al.s, ql[ks].s, acc);
            }
            accA[c*4 + mt] = acc;
        }

        // fused MLP — plain scalar fp32 (no inline asm; isolates the R5 bug)
        float mix[16];
#pragma unroll
        for (int i = 0; i < 16; ++i) mix[i] = b2v;
#pragma unroll 1
        for (int cc = 0; cc < 16; ++cc) {
            const float w1d = smF[9216 + 4*cc + 0];
            const float w1s = smF[9216 + 4*cc + 1];
            const float bb1 = smF[9216 + 4*cc + 2];
            const float ww2 = smF[9216 + 4*cc + 3];
#pragma unroll
            for (int mt = 0; mt < 4; ++mt) {
#pragma unroll
                for (int r = 0; r < 4; ++r) {
                    const float hh = fmaf(accA[c*4+mt][r], w1d,
                                          fmaf(dv[mt][r], w1s, bb1));
                    mix[mt*4+r] = fmaf(fmaxf(hh, 0.f), ww2, mix[mt*4+r]);
                }
            }
        }
#pragma unroll
        for (int mt = 0; mt < 4; ++mt)
            accA[c*4+mt] = fx4{mix[mt*4+0], mix[mt*4+1], mix[mt*4+2], mix[mt*4+3]};

        if (c < 7) {
            const int nxt = 4608 - cur;
#pragma unroll
            for (int it = 0; it < 4; ++it) {
                uint32_t h0,l0,h1,l1;
                packsplit(knext[it].x, knext[it].y, h0, l0);
                packsplit(knext[it].z, knext[it].w, h1, l1);
                const int ro = (mrow + 16*it)*36 + 2*k4;
                *(uint2*)(sm + nxt + ro)        = make_uint2(h0,h1);
                *(uint2*)(sm + nxt + 2304 + ro) = make_uint2(l0,l1);
            }
        }
        __syncthreads();
    }

    // ============ prefetch Vt chunk 0, softmax overlapping loads ============
    fx4 vreg[2][2];
#pragma unroll
    for (int it = 0; it < 2; ++it) {
        const float* vr = vg + base + (size_t)(2*vm2)*64 + 4*(vd4 + 8*it);
        vreg[it][0] = *(const fx4*)vr;
        vreg[it][1] = *(const fx4*)(vr + 64);
    }

    // full-row softmax in registers (rows t=col, lanes Q=0..3 hold m-quarters)
    {
        float mx = -3.0e38f;
#pragma unroll
        for (int i = 0; i < 32; ++i)
#pragma unroll
            for (int r = 0; r < 4; ++r) mx = fmaxf(mx, accA[i][r]);
        mx = fmaxf(mx, __shfl_xor(mx, 16, 64));
        mx = fmaxf(mx, __shfl_xor(mx, 32, 64));
        float sum = 0.f;
#pragma unroll
        for (int i = 0; i < 32; ++i)
#pragma unroll
            for (int r = 0; r < 4; ++r) {
                const float e = __expf(accA[i][r] - mx);
                accA[i][r] = e;
                sum += e;
            }
        sum += __shfl_xor(sum, 16, 64);
        sum += __shfl_xor(sum, 32, 64);
        const float rinv = 1.f / sum;
#pragma unroll
        for (int i = 0; i < 32; ++i)
#pragma unroll
            for (int r = 0; r < 4; ++r) accA[i][r] *= rinv;
    }

    // write Vt chunk 0 (bank-conflict-reduced: m2 varies across lanes)
#pragma unroll
    for (int it = 0; it < 2; ++it) {
        const int d4 = vd4 + 8*it;
#pragma unroll
        for (int i = 0; i < 4; ++i) {
            uint32_t hw, lw;
            packsplit(vreg[it][0][i], vreg[it][1][i], hw, lw);
            sm[(4*d4 + i)*36 + vm2]        = hw;
            sm[2304 + (4*d4 + i)*36 + vm2] = lw;
        }
    }
    __syncthreads();

    // ===================== PV phase (double-buffered) =====================
    const int sbase = col | ((lane & 16) << 1);   // col + 32*(Q&1)
#pragma unroll
    for (int c = 0; c < 8; ++c) {
        const int cur = (c & 1) * 4608;
        fx4 vnext[2][2];
        if (c < 7) {
#pragma unroll
            for (int it = 0; it < 2; ++it) {
                const float* vr = vg + base + (size_t)((c+1)*64 + 2*vm2)*64 + 4*(vd4 + 8*it);
                vnext[it][0] = *(const fx4*)vr;
                vnext[it][1] = *(const fx4*)(vr + 64);
            }
        }
#pragma unroll
        for (int s = 0; s < 2; ++s) {
            const fx4 e0 = accA[c*4 + 2*s], e1 = accA[c*4 + 2*s + 1];
            uint32_t ph[4], pl[4];
            packsplit(e0.x, e0.y, ph[0], pl[0]);
            packsplit(e0.z, e0.w, ph[1], pl[1]);
            packsplit(e1.x, e1.y, ph[2], pl[2]);
            packsplit(e1.z, e1.w, ph[3], pl[3]);
            Frag Ah, Al;
#pragma unroll
            for (int dd = 0; dd < 4; ++dd) {
                const int sl = sbase + ((dd >> 1) << 4);
                const int pi = dd & 1;
                uint32_t h0 = (uint32_t)__shfl((int)ph[pi],   sl, 64);
                uint32_t h1 = (uint32_t)__shfl((int)ph[2+pi], sl, 64);
                uint32_t l0 = (uint32_t)__shfl((int)pl[pi],   sl, 64);
                uint32_t l1 = (uint32_t)__shfl((int)pl[2+pi], sl, 64);
                Ah.u[dd] = (lane & 32) ? h1 : h0;
                Al.u[dd] = (lane & 32) ? l1 : l0;
            }
#pragma unroll
            for (int dt = 0; dt < 4; ++dt) {
                const int vo = cur + (dt*16 + col)*36 + s*16 + 4*Q;
                Frag bh_, bl_;
                bh_.s = *(short8*)(sm + vo);
                bl_.s = *(short8*)(sm + vo + 2304);
                oacc[dt] = MFMA(Ah.s, bh_.s, oacc[dt]);
                oacc[dt] = MFMA(Ah.s, bl_.s, oacc[dt]);
                oacc[dt] = MFMA(Al.s, bh_.s, oacc[dt]);
            }
        }
        if (c < 7) {
            const int nxt = 4608 - cur;
#pragma unroll
            for (int it = 0; it < 2; ++it) {
                const int d4 = vd4 + 8*it;
#pragma unroll
                for (int i = 0; i < 4; ++i) {
                    uint32_t hw, lw;
                    packsplit(vnext[it][0][i], vnext[it][1][i], hw, lw);
                    sm[nxt + (4*d4 + i)*36 + vm2]        = hw;
                    sm[nxt + 2304 + (4*d4 + i)*36 + vm2] = lw;
                }
            }
        }
        __syncthreads();
    }

    // epilogue: O rows t = w*16 + 4Q + r, cols d = dt*16 + col
    const size_t ob = ((size_t)b*512 + t0g + w*16 + 4*Q)*1024 + h*64 + col;
#pragma unroll
    for (int dt = 0; dt < 4; ++dt) {
        const fx4 o4 = oacc[dt];
#pragma unroll
        for (int r = 0; r < 4; ++r)
            outg[ob + (size_t)r*1024 + dt*16] = o4[r];
    }
}

extern "C" void kernel_launch(void* const* d_in, const int* in_sizes, int n_in,
                              void* d_out, int out_size, void* d_ws, size_t ws_size,
                              hipStream_t stream) {
    const float* q   = (const float*)d_in[0];
    const float* k   = (const float*)d_in[1];
    const float* v   = (const float*)d_in[2];
    const float* dtm = (const float*)d_in[3];
    const float* m1w = (const float*)d_in[4];
    const float* m1b = (const float*)d_in[5];
    const float* m2w = (const float*)d_in[6];
    const float* m2b = (const float*)d_in[7];
    float* out = (float*)d_out;

    dim3 grid(64 * 8);    // (b,h) x 8 T-tiles of 64 rows
    dim3 block(256);
    msmha_v7<<<grid, block, 0, stream>>>(q, k, v, dtm, m1w, m1b, m2w, m2b, out);
}